// Round 3
// baseline (51.517 us; speedup 1.0000x reference)
//
#include <hip/hip_runtime.h>
#include <stdint.h>

// Problem constants
#define NINq   512
#define DIMq   64
#define NHEADq 8
#define Bq     2
#define Nq     2048
#define MTOT   4096          // B*N rows
#define CHELEM 131072        // 2048*64 elements per chunk

typedef __attribute__((ext_vector_type(4))) float   f32x4;
typedef __attribute__((ext_vector_type(8))) short   bh8;     // 8 bf16 in 4 VGPRs
typedef __attribute__((ext_vector_type(4))) unsigned short u16x4;
typedef unsigned short u16;

__device__ inline u16 f2bf(float f) {
    union { float f; uint32_t u; } v; v.f = f;
    uint32_t u = v.u;
    u += 0x7FFF + ((u >> 16) & 1);         // RNE
    return (u16)(u >> 16);
}

__device__ inline void gload_lds16(const u16* g, u16* l) {
    __builtin_amdgcn_global_load_lds(
        (const __attribute__((address_space(1))) uint32_t*)g,
        (__attribute__((address_space(3)))       uint32_t*)l,
        16, 0, 0);
}

// ---------------- K0: convert x, Wq, Wk, Wv to bf16 ----------------
__global__ __launch_bounds__(256) void k0_convert(
        const float* __restrict__ x,
        const float* __restrict__ Wq,
        const float* __restrict__ Wk,
        const float* __restrict__ Wv,
        u16* __restrict__ xb, u16* __restrict__ Wb) {
    int idx = blockIdx.x * 256 + threadIdx.x;   // float4 index, 720896 total
    const float4* src; u16* dst; int off;
    if (idx < 524288) { src = (const float4*)x; dst = xb; off = idx; }
    else {
        int j = idx - 524288;
        int w = j >> 16;                        // 65536 float4 per W
        off = j & 65535;
        src = (const float4*)(w == 0 ? Wq : (w == 1 ? Wk : Wv));
        dst = Wb + w * (512 * 512);
    }
    float4 f = src[off];
    u16x4 o;
    o[0] = f2bf(f.x); o[1] = f2bf(f.y); o[2] = f2bf(f.z); o[3] = f2bf(f.w);
    *(u16x4*)(dst + off * 4) = o;
}

// ---------------- K1: QKV projection GEMM ----------------
// C[m,n] = sum_k xb[m,k] * W[n,k] + bias[n]   (gemm_bt), 128x128 tile, BK=64
// Q (w==0): stored straight [4096][512].
// K,V (w==1,2): stored TRANSPOSED per chunk: Kt2[c][d][nh][m8], c=m>>8,
//   d=n&63, nh=n>>6, m8=m&255  (chunk row r = m8*8+nh; kidx=nh*256+m8 is a
//   fixed permutation of r, identical for K and V, so K2's contraction is exact).
__global__ __launch_bounds__(256) void k1_qkv(
        const u16* __restrict__ xb, const u16* __restrict__ Wb,
        const float* __restrict__ bq, const float* __restrict__ bk,
        const float* __restrict__ bv,
        u16* __restrict__ Qb, u16* __restrict__ Kb, u16* __restrict__ Vb) {
    __shared__ u16 smem[16640];                 // main: lA[8192]+lB[8192]; epi: tile[128][130]
    u16* lA = smem;
    u16* lB = smem + 8192;
    const int tid  = threadIdx.x;
    const int lane = tid & 63, wid = tid >> 6;
    const int wrow = wid >> 1, wcol = wid & 1;
    // XCD swizzle: 384 blocks, 8 XCDs, 48 consecutive per XCD
    const int flat = blockIdx.x;
    const int swz  = (flat & 7) * 48 + (flat >> 3);
    const int mb = swz / 12, nb = swz % 12;
    const int w    = nb >> 2;
    const int nloc = (nb & 3) * 128;
    const u16*   W    = Wb + w * (512 * 512);
    const float* bias = (w == 0) ? bq : ((w == 1) ? bk : bv);
    u16*         out  = (w == 0) ? Qb : ((w == 1) ? Kb : Vb);
    const int m0 = mb * 128;

    f32x4 acc[4][4] = {};
    const int srow = tid >> 3;
    const int scol = (tid & 7) * 8;

    for (int kb = 0; kb < 8; ++kb) {
        __syncthreads();
        const int k0 = kb * 64;
#pragma unroll
        for (int it = 0; it < 4; ++it) {
            int r = it * 32 + srow;
            gload_lds16(xb + (size_t)(m0 + r) * 512 + k0 + scol,  lA + r * 64 + scol);
            gload_lds16(W  + (size_t)(nloc + r) * 512 + k0 + scol, lB + r * 64 + scol);
        }
        asm volatile("s_waitcnt vmcnt(0)" ::: "memory");
        __syncthreads();
#pragma unroll
        for (int ks = 0; ks < 2; ++ks) {
            const int kk = ks * 32 + (lane >> 4) * 8;
            bh8 a[4], b[4];
#pragma unroll
            for (int i = 0; i < 4; ++i) {
                a[i] = *(const bh8*)&lA[(wrow * 64 + i * 16 + (lane & 15)) * 64 + kk];
                b[i] = *(const bh8*)&lB[(wcol * 64 + i * 16 + (lane & 15)) * 64 + kk];
            }
#pragma unroll
            for (int i = 0; i < 4; ++i)
#pragma unroll
                for (int j = 0; j < 4; ++j)
                    acc[i][j] = __builtin_amdgcn_mfma_f32_16x16x32_bf16(a[i], b[j], acc[i][j], 0, 0, 0);
        }
    }

    if (w == 0) {
        // straight store (Q)
#pragma unroll
        for (int i = 0; i < 4; ++i) {
            const int row_base = m0 + wrow * 64 + i * 16 + ((lane >> 4) * 4);
#pragma unroll
            for (int j = 0; j < 4; ++j) {
                const int col = nloc + wcol * 64 + j * 16 + (lane & 15);
                const float bv_ = bias[col];
#pragma unroll
                for (int r = 0; r < 4; ++r)
                    out[(size_t)(row_base + r) * 512 + col] = f2bf(acc[i][j][r] + bv_);
            }
        }
    } else {
        // transposed store (K, V) via padded LDS tile
        __syncthreads();                       // all waves done with lA/lB
        u16 (*tile)[130] = (u16(*)[130])smem;
#pragma unroll
        for (int i = 0; i < 4; ++i) {
            const int mrow = wrow * 64 + i * 16 + ((lane >> 4) * 4);
#pragma unroll
            for (int j = 0; j < 4; ++j) {
                const int ncol = wcol * 64 + j * 16 + (lane & 15);
                const float bv_ = bias[nloc + ncol];
#pragma unroll
                for (int r = 0; r < 4; ++r)
                    tile[mrow + r][ncol] = f2bf(acc[i][j][r] + bv_);
            }
        }
        __syncthreads();
        const int c = mb >> 1;
        const int mbase = (mb & 1) * 128;      // m0 & 255
        const int a2 = (nb & 3) * 2;           // nh base
        u16* dstc = out + (size_t)c * CHELEM;
        const int eh   = (tid >> 4) & 1;
        const int mseg = (tid & 15) * 8;
        const int dhi  = tid >> 5;
#pragma unroll
        for (int db = 0; db < 8; ++db) {
            const int d = db * 8 + dhi;
            u16 tmp[8];
#pragma unroll
            for (int k = 0; k < 8; ++k)
                tmp[k] = tile[mseg + k][eh * 64 + d];
            const size_t off = (size_t)d * 2048 + (a2 + eh) * 256 + mbase + mseg;
            *(u16x4*)&dstc[off]     = *(u16x4*)&tmp[0];
            *(u16x4*)&dstc[off + 4] = *(u16x4*)&tmp[4];
        }
    }
}

// ---------------- K2: Pb[c][d][e] = scale * sum_k Vt2[c][d][k] * Kt2[c][e][k] ----------------
// 16 blocks (1/chunk), MFMA gemm_bt M=N=64 K=2048, 4-deep LDS ring, counted vmcnt.
__global__ __launch_bounds__(256) void k2_pmat(
        const u16* __restrict__ Kt2, const u16* __restrict__ Vt2,
        u16* __restrict__ Pb) {
    __shared__ u16 lds[4][8192];               // per buf: [0..4095]=A(V), [4096..8191]=B(K)
    const int tid  = threadIdx.x;
    const int lane = tid & 63, w = tid >> 6;
    const int c = blockIdx.x;
    const u16* Ac = Vt2 + (size_t)c * CHELEM;
    const u16* Bc = Kt2 + (size_t)c * CHELEM;

    f32x4 acc[4] = {};
    const int srow0 = tid >> 3;                // 0..31
    const int scol  = (tid & 7) * 8;

    auto stage = [&](int s) {
        const int k0 = s * 64;
        u16* buf = lds[s & 3];
#pragma unroll
        for (int g = 0; g < 2; ++g) {
            const int row = g * 32 + srow0;
            const int col = scol ^ ((row & 7) << 3);    // pre-swizzled source (T2 both-sides)
            gload_lds16(Ac + row * 2048 + k0 + col, buf + (g * 256 + tid) * 8);
            gload_lds16(Bc + row * 2048 + k0 + col, buf + 4096 + (g * 256 + tid) * 8);
        }
    };
    const int arow   = w * 16 + (lane & 15);
    const int kxbase = (lane & 7) << 3;
    auto compute = [&](int t) {
        const u16* buf = lds[t & 3];
#pragma unroll
        for (int ks = 0; ks < 2; ++ks) {
            const int kk = (ks * 32 + ((lane >> 4) * 8)) ^ kxbase;   // swizzled read
            bh8 a = *(const bh8*)&buf[arow * 64 + kk];
#pragma unroll
            for (int eg = 0; eg < 4; ++eg) {
                const int erow = eg * 16 + (lane & 15);
                bh8 b = *(const bh8*)&buf[4096 + erow * 64 + kk];
                acc[eg] = __builtin_amdgcn_mfma_f32_16x16x32_bf16(a, b, acc[eg], 0, 0, 0);
            }
        }
    };

    stage(0); stage(1); stage(2);              // 12 loads/wave outstanding
#define K2_SLICE(T, VM) \
    { if ((T) + 3 < 32) stage((T) + 3); \
      asm volatile("s_waitcnt vmcnt(" #VM ")" ::: "memory"); \
      __builtin_amdgcn_s_barrier(); \
      compute(T); \
      __builtin_amdgcn_s_barrier(); }
    for (int t = 0; t < 29; ++t) { K2_SLICE(t, 12); }
    K2_SLICE(29, 8)
    K2_SLICE(30, 4)
    K2_SLICE(31, 0)
#undef K2_SLICE

    u16* Pc = Pb + c * 4096;
#pragma unroll
    for (int eg = 0; eg < 4; ++eg) {
        const int e = eg * 16 + (lane & 15);
#pragma unroll
        for (int r = 0; r < 4; ++r) {
            const int d = w * 16 + (lane >> 4) * 4 + r;
            Pc[d * 64 + e] = f2bf(acc[eg][r] * 0.125f);   // scale = DIM^-0.5
        }
    }
}

// ---------------- K3: out_c = Q_c @ P_c^T  (K=64 per head, no LDS) ----------------
__global__ __launch_bounds__(256) void k3_out(
        const u16* __restrict__ Qb, const u16* __restrict__ Pb,
        float* __restrict__ outp) {
    const int tid = threadIdx.x;
    const int lane = tid & 63, w = tid >> 6;
    const int bb = blockIdx.x >> 6;          // 128 blocks: 64 row-blocks per bb
    const int ib = blockIdx.x & 63;
    const int i0 = ib * 32 + (w >> 1) * 16;  // row base within batch (A-frag rows)
    const int dbase = (w & 1) * 32;
    const int krow = lane & 15;
    const int koff = (lane >> 4) * 8;

    f32x4 acc[8][2] = {};                    // [head][nf]
#pragma unroll
    for (int h = 0; h < 8; ++h) {
        const int c = h * 2 + bb;
        const u16* Qc = Qb + (size_t)c * CHELEM;
        const u16* Pc = Pb + c * 4096;
#pragma unroll
        for (int ks = 0; ks < 2; ++ks) {
            bh8 a = *(const bh8*)&Qc[(i0 + krow) * 64 + ks * 32 + koff];
#pragma unroll
            for (int nf = 0; nf < 2; ++nf) {
                bh8 b = *(const bh8*)&Pc[(dbase + nf * 16 + krow) * 64 + ks * 32 + koff];
                acc[h][nf] = __builtin_amdgcn_mfma_f32_16x16x32_bf16(a, b, acc[h][nf], 0, 0, 0);
            }
        }
    }
    const int orow_base = bb * 2048 + ib * 32 + (w >> 1) * 16 + (lane >> 4) * 4;
#pragma unroll
    for (int nf = 0; nf < 2; ++nf) {
        const int d = dbase + nf * 16 + (lane & 15);
#pragma unroll
        for (int r = 0; r < 4; ++r) {
            f32x4 lo = {acc[0][nf][r], acc[1][nf][r], acc[2][nf][r], acc[3][nf][r]};
            f32x4 hi = {acc[4][nf][r], acc[5][nf][r], acc[6][nf][r], acc[7][nf][r]};
            float* dst = outp + (size_t)(orow_base + r) * 512 + d * 8;
            *(f32x4*)dst = lo;
            *(f32x4*)(dst + 4) = hi;
        }
    }
}

extern "C" void kernel_launch(void* const* d_in, const int* in_sizes, int n_in,
                              void* d_out, int out_size, void* d_ws, size_t ws_size,
                              hipStream_t stream) {
    const float* x  = (const float*)d_in[0];
    const float* Wq = (const float*)d_in[1];
    const float* bq = (const float*)d_in[2];
    const float* Wk = (const float*)d_in[3];
    const float* bk = (const float*)d_in[4];
    const float* Wv = (const float*)d_in[5];
    const float* bv = (const float*)d_in[6];
    float* outp = (float*)d_out;

    u16* xb = (u16*)d_ws;                 // 4096*512
    u16* Wb = xb + 2097152;               // 3*512*512
    u16* Qb = Wb + 786432;                // 4096*512 (straight)
    u16* Kb = Qb + 2097152;               // transposed chunks
    u16* Vb = Kb + 2097152;               // transposed chunks
    u16* Pb = Vb + 2097152;               // 16*64*64

    k0_convert<<<2816, 256, 0, stream>>>(x, Wq, Wk, Wv, xb, Wb);
    k1_qkv<<<384, 256, 0, stream>>>(xb, Wb, bq, bk, bv, Qb, Kb, Vb);
    k2_pmat<<<16, 256, 0, stream>>>(Kb, Vb, Pb);
    k3_out<<<128, 256, 0, stream>>>(Qb, Pb, outp);
}